// Round 5
// baseline (85.416 us; speedup 1.0000x reference)
//
#include <hip/hip_runtime.h>
#include <math.h>

#define NS     32768             // samples per sequence
#define NB     128               // interpolation bins
#define CELL   16                // samples per thread-cell (never crosses a segment)
#define CPB    32                // cells per block (per head)
#define PART   (CELL * CPB)      // 512 samples per block-part
#define NPARTS (NS / PART)       // 64 parts per sequence
#define TPB    256               // thread = (cell c = tid>>3, head h = tid&7)
#define NBATCH 16
#define GRID   (NBATCH * NPARTS) // 1024 blocks

// sin(2*pi*x): v_sin_f32 takes revolutions; reduce to [-0.5, 0.5] first
__device__ __forceinline__ float sinr(float x) {
    return __builtin_amdgcn_sinf(x - rintf(x));
}

// linear-interp segment params for a 16-aligned cell at sample i
__device__ __forceinline__ void seg_params(int i, int& lo, int& hi,
                                           double& w0, double& wst) {
    if (i < 128)            { lo = 0;   hi = 1;   w0 = 0.0; wst = 0.0; }
    else if (i >= NS - 128) { lo = 127; hi = 127; w0 = 0.0; wst = 0.0; }
    else {
        lo = (i - 128) >> 8;  hi = lo + 1;
        int off = (i - 128) & 255;
        w0 = (off + 0.5) * (1.0 / 256.0);
        wst = 1.0 / 256.0;
    }
}

// bin value for stream q at bin j; phase streams (f0, std, modf) and b are
// pre-scaled to revolutions so all downstream phase math is in revolutions
__device__ __forceinline__ double bin_value(const float* xs, int q, int j) {
    const double PI_    = 3.14159265358979323846;
    const double INV2PI = 0.15915494309189533576888376337251;
    const double MINF   = 40.0 / 11025.0;
    const double FRNG   = (4000.0 - 40.0) / 11025.0;
    if (q == 0) {                                   // amp (unscaled)
        double a0 = (double)xs[j], a1 = (double)xs[NB + j];
        return sqrt(a0 * a0 + a1 * a1);
    }
    double ang = atan2((double)xs[(2 * q - 1) * NB + j],
                       (double)xs[(2 * q - 2) * NB + j]) / PI_;
    double sh, sc;
    if      (q == 1) { sh = MINF; sc = FRNG; }      // f0
    else if (q == 2) { sh = 1.0;  sc = 0.5;  }      // mix (amplitude, unscaled)
    else if (q == 3) { sh = MINF; sc = FRNG; }      // noise_std
    else if (q == 4) { sh = 0.25; sc = 4.75; }      // mod_factor
    else             { sh = 0.1;  sc = 9.9;  }      // b
    double v = sh + ang * sc;
    if (q != 2) v *= INV2PI;
    return v;
}

// closed-form f64 cell totals {t1=cs1, t3=cs3, t2=cs2} over 16 samples
__device__ __forceinline__ void cell_totals(
        const float4* nn, double f0L, double dF0, double stL, double dSt,
        double mfL, double dMf, double w0, double wst,
        double& t1, double& t3, double& t2) {
    float4 A0 = nn[0], A1 = nn[1], A2 = nn[2], A3 = nn[3];
    float nf[CELL] = {A0.x, A0.y, A0.z, A0.w, A1.x, A1.y, A1.z, A1.w,
                      A2.x, A2.y, A2.z, A2.w, A3.x, A3.y, A3.z, A3.w};
    double S0 = 0.0, S1 = 0.0;
    #pragma unroll
    for (int j = 0; j < CELL; ++j) {
        S0 += (double)nf[j];
        S1 += (double)j * (double)nf[j];
    }
    double sw = 16.0 * w0 + 120.0 * wst;            // sum of w over the cell
    t3 = 16.0 * f0L + dF0 * sw;
    t2 = 16.0 * mfL + dMf * sw;
    t1 = t3 + stL * S0 + dSt * (w0 * S0 + wst * S1);
}

// ---- phase A: per-(batch,part) span totals {cs1,cs3,cs2} -> wspan[seq][part][3]
__global__ __launch_bounds__(TPB, 4)
void span_kernel(const float* __restrict__ xg, const float* __restrict__ ng,
                 double* __restrict__ wspan) {
    __shared__ double binsA[8][3][4];      // f0, std, modf @ bins b0..b0+3
    __shared__ double wtot[4][8][3];

    int bx = blockIdx.x, b = bx >> 6, p = bx & (NPARTS - 1);
    int tid = threadIdx.x, lane = tid & 63, wid = tid >> 6;
    int h = tid & 7, c = tid >> 3;
    int P = p * PART;
    int b0 = (P - 128) >> 8; if (b0 < 0) b0 = 0;

    int s  = (b << 3) + h;
    int i0 = P + c * CELL;
    const float4* nn = reinterpret_cast<const float4*>(ng + (size_t)s * NS + i0);

    if (tid < 96) {                        // 8 heads x 3 streams x 4 bins
        int j = tid & 3, r = (tid >> 2) % 3, h2 = tid / 12;
        int q = (r == 0) ? 1 : (r == 1) ? 3 : 4;
        const float* xs = xg + (size_t)((b << 3) + h2) * 10 * NB;
        binsA[h2][r][j] = bin_value(xs, q, min(b0 + j, NB - 1));
    }
    __syncthreads();

    int lo, hi; double w0, wst;
    seg_params(i0, lo, hi, w0, wst);
    int jL = lo - b0, jH = hi - b0;
    double f0L = binsA[h][0][jL], dF0 = binsA[h][0][jH] - f0L;
    double stL = binsA[h][1][jL], dSt = binsA[h][1][jH] - stL;
    double mfL = binsA[h][2][jL], dMf = binsA[h][2][jH] - mfL;

    double t1, t3, t2;
    cell_totals(nn, f0L, dF0, stL, dSt, mfL, dMf, w0, wst, t1, t3, t2);

    // in-wave scan over cells (stride 8 preserves head lane)
    double v1 = t1, v3 = t3, v2 = t2;
    #pragma unroll
    for (int d = 8; d < 64; d <<= 1) {
        double u1 = __shfl_up(v1, d);
        double u3 = __shfl_up(v3, d);
        double u2 = __shfl_up(v2, d);
        if (lane >= d) { v1 += u1; v3 += u3; v2 += u2; }
    }
    if (lane >= 56) { wtot[wid][h][0] = v1; wtot[wid][h][1] = v3; wtot[wid][h][2] = v2; }
    __syncthreads();
    if (tid < 24) {
        int hh = tid & 7, k = tid >> 3;
        double t = wtot[0][hh][k] + wtot[1][hh][k] + wtot[2][hh][k] + wtot[3][hh][k];
        wspan[((size_t)(((b << 3) + hh) * NPARTS) + p) * 3 + k] = t;
    }
}

// ---- phase B: full synth; anchors = span-prefix (L2) + in-block scan
__global__ __launch_bounds__(TPB, 4)
void fm2_kernel(const float* __restrict__ xg, const float* __restrict__ ng,
                const double* __restrict__ wspan, float* __restrict__ out) {
    __shared__ double binsA[8][3][4];
    __shared__ float  binsB[8][6][4];
    __shared__ double wtot[4][8][3];
    __shared__ double pref[8][3];

    int bx = blockIdx.x, b = bx >> 6, p = bx & (NPARTS - 1);
    int tid = threadIdx.x, lane = tid & 63, wid = tid >> 6;
    int h = tid & 7, c = tid >> 3;
    int P = p * PART;
    int b0 = (P - 128) >> 8; if (b0 < 0) b0 = 0;

    int s  = (b << 3) + h;
    int i0 = P + c * CELL;
    const float4* nn = reinterpret_cast<const float4*>(ng + (size_t)s * NS + i0);
    float4 A0 = nn[0], A1 = nn[1], A2 = nn[2], A3 = nn[3];

    if (tid < 192) {                       // waves 0-2: bins (8h x 6q x 4j)
        int j = tid & 3, q = (tid >> 2) % 6, h2 = tid / 24;
        const float* xs = xg + (size_t)((b << 3) + h2) * 10 * NB;
        double v = bin_value(xs, q, min(b0 + j, NB - 1));
        binsB[h2][q][j] = (float)v;
        if      (q == 1) binsA[h2][0][j] = v;
        else if (q == 3) binsA[h2][1][j] = v;
        else if (q == 4) binsA[h2][2][j] = v;
    } else if (tid < 216) {                // wave 3: span prefix over parts < p
        int t2 = tid - 192, hh = t2 & 7, k = t2 >> 3;
        const double* sp = wspan + ((size_t)(((b << 3) + hh) * NPARTS)) * 3 + k;
        double acc = 0.0;
        for (int q2 = 0; q2 < p; ++q2) acc += sp[q2 * 3];
        pref[hh][k] = acc;
    }
    __syncthreads();

    int lo, hi; double w0, wst;
    seg_params(i0, lo, hi, w0, wst);
    int jL = lo - b0, jH = hi - b0;
    double f0L = binsA[h][0][jL], dF0 = binsA[h][0][jH] - f0L;
    double stL = binsA[h][1][jL], dSt = binsA[h][1][jH] - stL;
    double mfL = binsA[h][2][jL], dMf = binsA[h][2][jH] - mfL;

    double t1, t3, t2;
    cell_totals(nn, f0L, dF0, stL, dSt, mfL, dMf, w0, wst, t1, t3, t2);

    double v1 = t1, v3 = t3, v2 = t2;
    #pragma unroll
    for (int d = 8; d < 64; d <<= 1) {
        double u1 = __shfl_up(v1, d);
        double u3 = __shfl_up(v3, d);
        double u2 = __shfl_up(v2, d);
        if (lane >= d) { v1 += u1; v3 += u3; v2 += u2; }
    }
    if (lane >= 56) { wtot[wid][h][0] = v1; wtot[wid][h][1] = v3; wtot[wid][h][2] = v2; }
    __syncthreads();
    double b1 = 0.0, b3 = 0.0, b2 = 0.0;
    #pragma unroll
    for (int k = 0; k < 3; ++k)
        if (wid > k) { b1 += wtot[k][h][0]; b3 += wtot[k][h][1]; b2 += wtot[k][h][2]; }

    // exact f64 anchors (exclusive prefix at cell start) -> f32 fractional rev
    double a1 = pref[h][0] + b1 + (v1 - t1);
    double a3 = pref[h][1] + b3 + (v3 - t3);
    double a2 = pref[h][2] + b2 + (v2 - t2);
    float fr1 = (float)(a1 - rint(a1));
    float fr3 = (float)(a3 - rint(a3));
    float fr2 = (float)(a2 - rint(a2));

    float amL = binsB[h][0][jL], dAm = binsB[h][0][jH] - amL;
    float g0L = binsB[h][1][jL], gF0 = binsB[h][1][jH] - g0L;
    float mxL = binsB[h][2][jL], dMx = binsB[h][2][jH] - mxL;
    float gsL = binsB[h][3][jL], gSt = binsB[h][3][jH] - gsL;
    float gmL = binsB[h][4][jL], gMf = binsB[h][4][jH] - gmL;
    float bbL = binsB[h][5][jL], dBb = binsB[h][5][jH] - bbL;
    float w0f = (float)w0, wsf = (float)wst;

    float nf[CELL] = {A0.x, A0.y, A0.z, A0.w, A1.x, A1.y, A1.z, A1.w,
                      A2.x, A2.y, A2.z, A2.w, A3.x, A3.y, A3.z, A3.w};
    float arr[CELL];
    float d1 = 0.f, d2 = 0.f, d3 = 0.f;
    #pragma unroll
    for (int j = 0; j < CELL; ++j) {
        float wf  = fmaf((float)j, wsf, w0f);
        float f0v = fmaf(wf, gF0, g0L);
        float stv = fmaf(wf, gSt, gsL);
        float mfv = fmaf(wf, gMf, gmL);
        d3 += f0v;                       // cs3 (rev, relative to anchor)
        d1 += fmaf(nf[j], stv, f0v);     // cs1
        d2 += mfv;                       // cs2
        float ampv = fmaf(wf, dAm, amL);
        float mixv = fmaf(wf, dMx, mxL);
        float bv   = fmaf(wf, dBb, bbL);
        float s2 = sinr(fr2 + d2);
        float s1 = sinr(fr1 + d1);
        float s3 = sinr(fmaf(bv, s2, fr3 + d3));
        float harm = ampv * mixv;
        arr[j] = fmaf(harm, s3, (ampv - harm) * s1);
    }

    // head-mean: butterfly over lane bits 0..2
    #pragma unroll
    for (int m = 1; m <= 4; m <<= 1) {
        #pragma unroll
        for (int j = 0; j < CELL; ++j) arr[j] += __shfl_xor(arr[j], m);
    }
    if (h == 0) {
        float4* op = reinterpret_cast<float4*>(out + (size_t)b * NS + i0);
        #pragma unroll
        for (int j4 = 0; j4 < 4; ++j4)
            op[j4] = make_float4(arr[j4 * 4 + 0] * 0.125f, arr[j4 * 4 + 1] * 0.125f,
                                 arr[j4 * 4 + 2] * 0.125f, arr[j4 * 4 + 3] * 0.125f);
    }
}

extern "C" void kernel_launch(void* const* d_in, const int* in_sizes, int n_in,
                              void* d_out, int out_size, void* d_ws, size_t ws_size,
                              hipStream_t stream) {
    const float* x     = (const float*)d_in[0];
    const float* noise = (const float*)d_in[1];
    float* out = (float*)d_out;
    double* wspan = (double*)d_ws;   // [128 seq][64 part][3] f64 = 196608 B
    span_kernel<<<GRID, TPB, 0, stream>>>(x, noise, wspan);
    fm2_kernel<<<GRID, TPB, 0, stream>>>(x, noise, wspan, out);
}

// Round 6
// 81.581 us; speedup vs baseline: 1.0470x; 1.0470x over previous
//
#include <hip/hip_runtime.h>
#include <math.h>

#define NS     32768             // samples per sequence
#define NB     128               // interpolation bins
#define CELL   16                // samples per thread-cell (never crosses a segment)
#define CPB    32                // cells per part
#define PART   (CELL * CPB)      // 512 samples
#define NPARTS (NS / PART)       // 64 parts per sequence
#define TPB    256
#define NBATCH 16
#define GRID   (NBATCH * NPARTS) // 1024 blocks
#define NCELL  (NS / CELL)       // 2048 cells per sequence

// sin(2*pi*x): v_sin_f32 takes revolutions; reduce to [-0.5, 0.5] first
__device__ __forceinline__ float sinr(float x) {
    return __builtin_amdgcn_sinf(x - rintf(x));
}

// linear-interp segment params for a 16-aligned cell at sample i
__device__ __forceinline__ void seg_params(int i, int& lo, int& hi,
                                           double& w0, double& wst) {
    if (i < 128)            { lo = 0;   hi = 1;   w0 = 0.0; wst = 0.0; }
    else if (i >= NS - 128) { lo = 127; hi = 127; w0 = 0.0; wst = 0.0; }
    else {
        lo = (i - 128) >> 8;  hi = lo + 1;
        int off = (i - 128) & 255;
        w0 = (off + 0.5) * (1.0 / 256.0);
        wst = 1.0 / 256.0;
    }
}

// bin value for stream q at bin j; phase streams (f0, std, modf) and b are
// pre-scaled to revolutions so all downstream phase math is in revolutions
__device__ __forceinline__ double bin_value(const float* xs, int q, int j) {
    const double PI_    = 3.14159265358979323846;
    const double INV2PI = 0.15915494309189533576888376337251;
    const double MINF   = 40.0 / 11025.0;
    const double FRNG   = (4000.0 - 40.0) / 11025.0;
    if (q == 0) {                                   // amp (unscaled)
        double a0 = (double)xs[j], a1 = (double)xs[NB + j];
        return sqrt(a0 * a0 + a1 * a1);
    }
    double ang = atan2((double)xs[(2 * q - 1) * NB + j],
                       (double)xs[(2 * q - 2) * NB + j]) / PI_;
    double sh, sc;
    if      (q == 1) { sh = MINF; sc = FRNG; }      // f0
    else if (q == 2) { sh = 1.0;  sc = 0.5;  }      // mix (amplitude, unscaled)
    else if (q == 3) { sh = MINF; sc = FRNG; }      // noise_std
    else if (q == 4) { sh = 0.25; sc = 4.75; }      // mod_factor
    else             { sh = 0.1;  sc = 9.9;  }      // b
    double v = sh + ang * sc;
    if (q != 2) v *= INV2PI;
    return v;
}

// closed-form f64 cell totals {t1=cs1, t3=cs3, t2=cs2} over 16 samples
__device__ __forceinline__ void cell_totals(
        const float4* nn, double f0L, double dF0, double stL, double dSt,
        double mfL, double dMf, double w0, double wst,
        double& t1, double& t3, double& t2) {
    float4 A0 = nn[0], A1 = nn[1], A2 = nn[2], A3 = nn[3];
    float nf[CELL] = {A0.x, A0.y, A0.z, A0.w, A1.x, A1.y, A1.z, A1.w,
                      A2.x, A2.y, A2.z, A2.w, A3.x, A3.y, A3.z, A3.w};
    double S0 = 0.0, S1 = 0.0;
    #pragma unroll
    for (int j = 0; j < CELL; ++j) {
        S0 += (double)nf[j];
        S1 += (double)j * (double)nf[j];
    }
    double sw = 16.0 * w0 + 120.0 * wst;            // sum of w over the cell
    t3 = 16.0 * f0L + dF0 * sw;
    t2 = 16.0 * mfL + dMf * sw;
    t1 = t3 + stL * S0 + dSt * (w0 * S0 + wst * S1);
}

// ---- K1: per-cell in-part exclusive prefixes + per-part span totals.
// Layout: h = tid>>5 (half-wave per head) so noise loads are 512B-coalesced
// and the 32-cell scan completes inside a half-wave (no cross-wave combine).
__global__ __launch_bounds__(TPB)
void span1_kernel(const float* __restrict__ xg, const float* __restrict__ ng,
                  double* __restrict__ wcell, double* __restrict__ wspan) {
    __shared__ double binsA[8][3][4];      // f0, std, modf @ bins b0..b0+3

    int bx = blockIdx.x, bb = bx >> 6, p = bx & (NPARTS - 1);
    int tid = threadIdx.x, lane = tid & 63;
    int h = tid >> 5, c = tid & 31;
    int P = p * PART;
    int b0 = (P - 128) >> 8; if (b0 < 0) b0 = 0;
    int s  = (bb << 3) + h;
    int i0 = P + c * CELL;

    if (tid < 96) {                        // 8 heads x 3 streams x 4 bins
        int j = tid & 3, r = (tid >> 2) % 3, h2 = tid / 12;
        int q = (r == 0) ? 1 : (r == 1) ? 3 : 4;
        const float* xs = xg + (size_t)((bb << 3) + h2) * 10 * NB;
        binsA[h2][r][j] = bin_value(xs, q, min(b0 + j, NB - 1));
    }
    __syncthreads();

    int lo, hi; double w0, wst;
    seg_params(i0, lo, hi, w0, wst);
    int jL = lo - b0, jH = hi - b0;
    double f0L = binsA[h][0][jL], dF0 = binsA[h][0][jH] - f0L;
    double stL = binsA[h][1][jL], dSt = binsA[h][1][jH] - stL;
    double mfL = binsA[h][2][jL], dMf = binsA[h][2][jH] - mfL;

    const float4* nn = reinterpret_cast<const float4*>(ng + (size_t)s * NS + i0);
    double t1, t3, t2;
    cell_totals(nn, f0L, dF0, stL, dSt, mfL, dMf, w0, wst, t1, t3, t2);

    // inclusive scan over the 32 cells of this head (within half-wave)
    double v1 = t1, v3 = t3, v2 = t2;
    #pragma unroll
    for (int d = 1; d < 32; d <<= 1) {
        double u1 = __shfl_up(v1, d);
        double u3 = __shfl_up(v3, d);
        double u2 = __shfl_up(v2, d);
        if ((lane & 31) >= d) { v1 += u1; v3 += u3; v2 += u2; }
    }

    size_t cb = ((size_t)s * NCELL + (size_t)p * CPB + c) * 3;
    wcell[cb + 0] = v1 - t1;               // exclusive in-part prefix
    wcell[cb + 1] = v3 - t3;
    wcell[cb + 2] = v2 - t2;
    if (c == 31) {                         // part span total
        size_t sb = ((size_t)s * NPARTS + p) * 3;
        wspan[sb + 0] = v1; wspan[sb + 1] = v3; wspan[sb + 2] = v2;
    }
}

// ---- K2: f32 bins for all streams + parallel shfl scan of span totals
__global__ __launch_bounds__(TPB)
void fix_kernel(const float* __restrict__ xg, const double* __restrict__ wspan,
                double* __restrict__ wpref, float* __restrict__ wbins) {
    int s = blockIdx.x, tid = threadIdx.x, lane = tid & 63, wid = tid >> 6;
    const float* xs = xg + (size_t)s * 10 * NB;
    #pragma unroll
    for (int r = 0; r < 3; ++r) {
        int idx = tid + r * TPB;           // [0, 768): q = idx>>7, j = idx&127
        wbins[(size_t)s * 768 + idx] = (float)bin_value(xs, idx >> 7, idx & 127);
    }
    if (wid < 3) {                         // wave k scans stream k over 64 parts
        int k = wid;
        double t = wspan[((size_t)s * NPARTS + lane) * 3 + k];
        double v = t;
        #pragma unroll
        for (int d = 1; d < 64; d <<= 1) {
            double u = __shfl_up(v, d);
            if (lane >= d) v += u;
        }
        wpref[((size_t)s * NPARTS + lane) * 3 + k] = v - t;   // exclusive
    }
}

// ---- K3: zero barriers / zero LDS; pure-f32 synth from f64 anchors
__global__ __launch_bounds__(TPB)
void fm3_kernel(const float* __restrict__ ng, const double* __restrict__ wcell,
                const double* __restrict__ wpref, const float* __restrict__ wbins,
                float* __restrict__ out) {
    int bx = blockIdx.x, bb = bx >> 6, p = bx & (NPARTS - 1);
    int tid = threadIdx.x;
    int h = tid & 7, c = tid >> 3;         // butterfly needs h in lane bits 0..2
    int P = p * PART, i0 = P + c * CELL;
    int s = (bb << 3) + h;

    int lo, hi; double w0, wst;
    seg_params(i0, lo, hi, w0, wst);

    // exact f64 anchors = in-part prefix + cross-part prefix -> f32 frac rev
    size_t cb = ((size_t)s * NCELL + (size_t)p * CPB + c) * 3;
    size_t pb = ((size_t)s * NPARTS + p) * 3;
    double a1 = wcell[cb + 0] + wpref[pb + 0];
    double a3 = wcell[cb + 1] + wpref[pb + 1];
    double a2 = wcell[cb + 2] + wpref[pb + 2];
    float fr1 = (float)(a1 - rint(a1));
    float fr3 = (float)(a3 - rint(a3));
    float fr2 = (float)(a2 - rint(a2));

    const float* B = wbins + (size_t)s * 768;
    float amL = B[lo],       dAm = B[hi] - amL;
    float g0L = B[128 + lo], gF0 = B[128 + hi] - g0L;
    float mxL = B[256 + lo], dMx = B[256 + hi] - mxL;
    float gsL = B[384 + lo], gSt = B[384 + hi] - gsL;
    float gmL = B[512 + lo], gMf = B[512 + hi] - gmL;
    float bbL = B[640 + lo], dBb = B[640 + hi] - bbL;
    float w0f = (float)w0, wsf = (float)wst;

    const float4* nn = reinterpret_cast<const float4*>(ng + (size_t)s * NS + i0);
    float4 A0 = nn[0], A1 = nn[1], A2 = nn[2], A3 = nn[3];
    float nf[CELL] = {A0.x, A0.y, A0.z, A0.w, A1.x, A1.y, A1.z, A1.w,
                      A2.x, A2.y, A2.z, A2.w, A3.x, A3.y, A3.z, A3.w};

    float arr[CELL];
    float d1 = 0.f, d2 = 0.f, d3 = 0.f;
    #pragma unroll
    for (int j = 0; j < CELL; ++j) {
        float wf  = fmaf((float)j, wsf, w0f);
        float f0v = fmaf(wf, gF0, g0L);
        float stv = fmaf(wf, gSt, gsL);
        float mfv = fmaf(wf, gMf, gmL);
        d3 += f0v;                       // cs3 (rev, relative to anchor)
        d1 += fmaf(nf[j], stv, f0v);     // cs1
        d2 += mfv;                       // cs2
        float ampv = fmaf(wf, dAm, amL);
        float mixv = fmaf(wf, dMx, mxL);
        float bv   = fmaf(wf, dBb, bbL);
        float s2 = sinr(fr2 + d2);
        float s1 = sinr(fr1 + d1);
        float s3 = sinr(fmaf(bv, s2, fr3 + d3));
        float harm = ampv * mixv;
        arr[j] = fmaf(harm, s3, (ampv - harm) * s1);
    }

    // head-mean: butterfly over lane bits 0..2
    #pragma unroll
    for (int m = 1; m <= 4; m <<= 1) {
        #pragma unroll
        for (int j = 0; j < CELL; ++j) arr[j] += __shfl_xor(arr[j], m);
    }
    if (h == 0) {
        float4* op = reinterpret_cast<float4*>(out + (size_t)bb * NS + i0);
        #pragma unroll
        for (int j4 = 0; j4 < 4; ++j4)
            op[j4] = make_float4(arr[j4 * 4 + 0] * 0.125f, arr[j4 * 4 + 1] * 0.125f,
                                 arr[j4 * 4 + 2] * 0.125f, arr[j4 * 4 + 3] * 0.125f);
    }
}

extern "C" void kernel_launch(void* const* d_in, const int* in_sizes, int n_in,
                              void* d_out, int out_size, void* d_ws, size_t ws_size,
                              hipStream_t stream) {
    const float* x     = (const float*)d_in[0];
    const float* noise = (const float*)d_in[1];
    float* out = (float*)d_out;
    // ws: wcell [128][2048][3] f64 (6.29 MB) | wspan [128][64][3] f64 (192 KB)
    //   | wpref [128][64][3] f64 (192 KB)    | wbins [128][6][128] f32 (384 KB)
    double* wcell = (double*)d_ws;
    double* wspan = wcell + (size_t)128 * NCELL * 3;
    double* wpref = wspan + (size_t)128 * NPARTS * 3;
    float*  wbins = (float*)(wpref + (size_t)128 * NPARTS * 3);
    span1_kernel<<<GRID, TPB, 0, stream>>>(x, noise, wcell, wspan);
    fix_kernel<<<128, TPB, 0, stream>>>(x, wspan, wpref, wbins);
    fm3_kernel<<<GRID, TPB, 0, stream>>>(noise, wcell, wpref, wbins, out);
}